// Round 4
// baseline (625.339 us; speedup 1.0000x reference)
//
#include <hip/hip_runtime.h>

typedef _Float16 f16;
typedef f16 f16x8 __attribute__((ext_vector_type(8)));
typedef f16 f16x4 __attribute__((ext_vector_type(4)));
typedef f16 f16x2 __attribute__((ext_vector_type(2)));
typedef float f32x4 __attribute__((ext_vector_type(4)));

// sizes
#define BDIM 16
#define CDIM 512
#define MDIM 4
#define NDIM 4096
#define NB   64          // n-columns per tile
#define NTILES (NDIM/NB) // 64
#define NBMT  (BDIM*MDIM*NTILES)  // 4096 (b,m,tile) rows

// LDS swizzle: spreads rows p across 8 16B slots; bijective per row
#define SX(p) ((((p)&7) ^ (((p)>>3)&7)))

// ---------------- prep: fp32 weights -> f16 fragment layout ----------------
// W1s: [e][kb(64)][o(128)][ki(8)]  (k = kb*8+ki, K=512)
// W2s: [e][kb(16)][o(48)][ki(8)]   (K=128)
// W3s: [e][kb(8)][o(16)][ki(8)]    (K=64, zero-padded from 48)
__global__ __launch_bounds__(256) void prep_kernel(
    const float* __restrict__ W1, const float* __restrict__ W2, const float* __restrict__ W3,
    f16* __restrict__ W1s, f16* __restrict__ W2s, f16* __restrict__ W3s)
{
  int i = blockIdx.x * 256 + threadIdx.x;
  if (i < 262144) {
    int ki = i & 7; int rest = i >> 3;
    int o = rest & 127; rest >>= 7;
    int kb = rest & 63; int e = rest >> 6;
    W1s[i] = (f16)W1[(e*128 + o)*512 + kb*8 + ki];
  } else if (i < 262144 + 24576) {
    int j = i - 262144;
    int ki = j & 7; int rest = j >> 3;
    int o = rest % 48; rest /= 48;
    int kb = rest & 15; int e = rest >> 4;
    W2s[j] = (f16)W2[(e*48 + o)*128 + kb*8 + ki];
  } else if (i < 262144 + 24576 + 4096) {
    int j = i - 262144 - 24576;
    int ki = j & 7; int rest = j >> 3;
    int o = rest & 15; rest >>= 4;
    int kb = rest & 7; int e = rest >> 3;
    int k = kb*8 + ki;
    W3s[j] = (k < 48) ? (f16)W3[(e*16 + o)*48 + k] : (f16)0.f;
  }
}

// ---------------- fused MoE expert pass (+ pool partials) ----------------
// block = (b, m, 64 n-columns) = bid; 512 threads = 8 waves.
// Phase A: K-chunked (8 x 64 channels, double-buffered LDS), L1 accumulated
//          in regs for ALL 4 experts; also reduces per-channel sums over the
//          64 positions -> partial[bid][c]  (pool fused, no extra x read).
// Phase B: per expert (unrolled): H1->LDS, L2, L3 -> h3 (f16, pre-combine).
// LDS (40 KiB): Xs 2x[64p][128B], H1t [64p][256B], H2t [64p][128B], swizzled.
__global__ __launch_bounds__(512, 2) void moe_kernel(
    const float* __restrict__ x,
    const f16* __restrict__ W1s, const f16* __restrict__ W2s, const f16* __restrict__ W3s,
    const float* __restrict__ b1, const float* __restrict__ b2, const float* __restrict__ b3,
    float* __restrict__ partial, f16* __restrict__ h3)
{
  __shared__ __align__(16) char smem[40960];
  char* Xs0 = smem;                 //  8192 B
  char* Xs1 = smem + 8192;          //  8192 B
  char* H1t = smem + 16384;         // 16384 B
  char* H2t = smem + 32768;         //  8192 B

  const int tid  = threadIdx.x;
  const int bid  = blockIdx.x;
  const int tile = bid & 63;
  const int m    = (bid >> 6) & 3;
  const int b    = bid >> 8;

  // zero H2t once (provides the K-pad h=48..63 for all experts)
  ((uint4*)H2t)[tid] = make_uint4(0u,0u,0u,0u);

  const int wave = tid >> 6, lane = tid & 63;
  const int g = lane >> 4, r = lane & 15;
  const int o0 = wave * 16;

  // staging coords: thread handles channel pair (2*cp, 2*cp+1), p-quad q*4..q*4+3
  const int cp = tid >> 4;          // 0..31
  const int q  = tid & 15;          // 0..15
  const float* xb = x + ((size_t)(b*2048 + m)) * 4096 + (size_t)tile*64
                      + (size_t)(2*cp)*16384 + q*4;
  float* prow = partial + (size_t)bid*512 + 2*cp;

  // prologue: stage chunk 0 (+ pool partial for chunk 0)
  {
    f32x4 v0 = *(const f32x4*)xb;
    f32x4 v1 = *(const f32x4*)(xb + 16384);
    #pragma unroll
    for (int i = 0; i < 4; ++i) {
      int p = q*4 + i;
      f16x2 hv; hv[0] = (f16)v0[i]; hv[1] = (f16)v1[i];
      *(f16x2*)(Xs0 + p*128 + ((4*cp) ^ (SX(p)<<4))) = hv;
    }
    float s0 = v0[0]+v0[1]+v0[2]+v0[3];
    float s1 = v1[0]+v1[1]+v1[2]+v1[3];
    #pragma unroll
    for (int off = 8; off; off >>= 1) {
      s0 += __shfl_down(s0, off, 16);
      s1 += __shfl_down(s1, off, 16);
    }
    if (q == 0) { float2 sv = {s0, s1}; *(float2*)prow = sv; }
  }

  f32x4 acc[4][4];
  #pragma unroll
  for (int e = 0; e < 4; ++e)
    #pragma unroll
    for (int pt = 0; pt < 4; ++pt) acc[e][pt] = (f32x4){0.f,0.f,0.f,0.f};

  // ---- Phase A: 8 chunks of 64 channels, double-buffered
  for (int ck = 0; ck < 8; ++ck) {
    __syncthreads();                       // chunk ck's buffer is ready
    f32x4 nv0, nv1;
    if (ck < 7) {                          // issue next chunk's loads early
      const float* src = xb + (size_t)(ck+1)*64*16384;
      nv0 = *(const f32x4*)src;
      nv1 = *(const f32x4*)(src + 16384);
    }
    const char* Xb = (ck & 1) ? Xs1 : Xs0;
    #pragma unroll
    for (int ks = 0; ks < 2; ++ks) {
      const int kbl = ks*4 + g;            // kb within chunk, 0..7
      const int kbg = ck*8 + kbl;          // global kb, 0..63
      f16x8 bf[4];
      #pragma unroll
      for (int pt = 0; pt < 4; ++pt) {
        int p = pt*16 + r;
        bf[pt] = *(const f16x8*)(Xb + p*128 + ((kbl*16) ^ (SX(p)<<4)));
      }
      #pragma unroll
      for (int e = 0; e < 4; ++e) {
        f16x8 a = *(const f16x8*)(W1s + ((size_t)((e*64 + kbg)*128) + o0 + r)*8);
        #pragma unroll
        for (int pt = 0; pt < 4; ++pt)
          acc[e][pt] = __builtin_amdgcn_mfma_f32_16x16x32_f16(a, bf[pt], acc[e][pt], 0, 0, 0);
      }
    }
    if (ck < 7) {                          // write next chunk into other buffer
      char* dst = (ck & 1) ? Xs0 : Xs1;
      #pragma unroll
      for (int i = 0; i < 4; ++i) {
        int p = q*4 + i;
        f16x2 hv; hv[0] = (f16)nv0[i]; hv[1] = (f16)nv1[i];
        *(f16x2*)(dst + p*128 + ((4*cp) ^ (SX(p)<<4))) = hv;
      }
      // pool partial for chunk ck+1 (data already in regs)
      float s0 = nv0[0]+nv0[1]+nv0[2]+nv0[3];
      float s1 = nv1[0]+nv1[1]+nv1[2]+nv1[3];
      #pragma unroll
      for (int off = 8; off; off >>= 1) {
        s0 += __shfl_down(s0, off, 16);
        s1 += __shfl_down(s1, off, 16);
      }
      if (q == 0) { float2 sv = {s0, s1}; *(float2*)(prow + (ck+1)*64) = sv; }
    }
  }

  // ---- Phase B: per expert chain (unrolled: acc[e] static indexing)
  #pragma unroll
  for (int e = 0; e < 4; ++e) {
    // H1 = relu(acc + b1) -> LDS [p][h]
    {
      const f32x4 bias = *(const f32x4*)(b1 + e*128 + o0 + g*4);
      const int ob = (o0 + g*4) * 2;       // byte col
      #pragma unroll
      for (int pt = 0; pt < 4; ++pt) {
        int p = pt*16 + r;
        f16x4 h;
        #pragma unroll
        for (int j = 0; j < 4; ++j) h[j] = (f16)fmaxf(acc[e][pt][j] + bias[j], 0.f);
        *(f16x4*)(H1t + p*256 + (ob ^ (SX(p)<<4))) = h;
      }
    }
    __syncthreads();

    // L2: H2 = relu(W2 @ H1 + b2); 12 fragments over 8 waves
    #pragma unroll
    for (int s = 0; s < 2; ++s) {
      int f = wave + s*8;
      if (f < 12) {
        int ot = f >> 2, pt = f & 3;
        int p = pt*16 + r;
        f32x4 acc2 = {0.f,0.f,0.f,0.f};
        #pragma unroll
        for (int ks = 0; ks < 4; ++ks) {
          int kb = ks*4 + g;
          f16x8 a  = *(const f16x8*)(W2s + (size_t)((e*16 + kb)*48 + ot*16 + r)*8);
          f16x8 bf = *(const f16x8*)(H1t + p*256 + ((kb*16) ^ (SX(p)<<4)));
          acc2 = __builtin_amdgcn_mfma_f32_16x16x32_f16(a, bf, acc2, 0, 0, 0);
        }
        const f32x4 bias = *(const f32x4*)(b2 + e*48 + ot*16 + g*4);
        const int ob = (ot*16 + g*4) * 2;
        f16x4 h;
        #pragma unroll
        for (int j = 0; j < 4; ++j) h[j] = (f16)fmaxf(acc2[j] + bias[j], 0.f);
        *(f16x4*)(H2t + p*128 + (ob ^ (SX(p)<<4))) = h;
      }
    }
    __syncthreads();

    // L3 -> h3 (pre-combine, f16) ; waves 0-3, pt = wave
    if (wave < 4) {
      const int pt = wave;
      int p = pt*16 + r;
      f32x4 acc3 = {0.f,0.f,0.f,0.f};
      #pragma unroll
      for (int ks = 0; ks < 2; ++ks) {
        int kb = ks*4 + g;
        f16x8 a  = *(const f16x8*)(W3s + (size_t)((e*8 + kb)*16 + r)*8);
        f16x8 bf = *(const f16x8*)(H2t + p*128 + ((kb*16) ^ (SX(p)<<4)));
        acc3 = __builtin_amdgcn_mfma_f32_16x16x32_f16(a, bf, acc3, 0, 0, 0);
      }
      const f32x4 bias = *(const f32x4*)(b3 + e*16 + g*4);
      #pragma unroll
      for (int j = 0; j < 4; ++j) {
        int o = g*4 + j;
        h3[(((size_t)(e*NBMT + bid))*16 + o)*64 + pt*16 + r] = (f16)(acc3[j] + bias[j]);
      }
    }
    // H1t rewrite (next e) fenced by post-L2 barrier; H2t rewrite by post-H1 barrier.
  }
}

// ---------------- gate: reduce partials -> pooled, MLP + softmax ----------
__global__ __launch_bounds__(256) void gate_kernel(
    const float* __restrict__ partial, const float* __restrict__ Wg1,
    const float* __restrict__ bg1, const float* __restrict__ Wg2,
    const float* __restrict__ bg2, float* __restrict__ wgt)
{
  __shared__ float pl[512*4];   // [c][m]
  __shared__ float g1[128*4];   // [o][m]
  __shared__ float g2[16];      // [e][m]
  const int b = blockIdx.x, tid = threadIdx.x;

  // reduce 64 tile-partials per (m, c): thread owns c-pair c0, c0+1
  const int c0 = tid * 2;
  #pragma unroll
  for (int mm = 0; mm < 4; ++mm) {
    const float* base = partial + ((size_t)((b*4 + mm)*64))*512 + c0;
    float a0 = 0.f, a1 = 0.f;
    for (int tl = 0; tl < 64; ++tl) {
      float2 v = *(const float2*)(base + tl*512);
      a0 += v.x; a1 += v.y;
    }
    pl[(c0+0)*4 + mm] = a0 * (1.0f/4096.0f);
    pl[(c0+1)*4 + mm] = a1 * (1.0f/4096.0f);
  }
  __syncthreads();

  #pragma unroll
  for (int u = 0; u < 2; ++u) {
    int idx = u*256 + tid;
    int o = idx >> 2, mm = idx & 3;
    float acc = bg1[o];
    for (int c = 0; c < 512; ++c) acc += Wg1[o*512 + c] * pl[c*4 + mm];
    g1[o*4 + mm] = fmaxf(acc, 0.f);
  }
  __syncthreads();
  if (tid < 16) {
    int e = tid >> 2, mm = tid & 3;
    float acc = bg2[e];
    for (int o = 0; o < 128; ++o) acc += Wg2[e*128 + o] * g1[o*4 + mm];
    g2[e*4 + mm] = acc;
  }
  __syncthreads();
  if (tid < 4) {
    // weights[b][m][e] = softmax_e over G[m][e], G[m][e] = g2[expert=m][modal=e]
    int mrow = tid;
    float v0 = g2[mrow*4+0], v1 = g2[mrow*4+1], v2 = g2[mrow*4+2], v3 = g2[mrow*4+3];
    float mx = fmaxf(fmaxf(v0,v1), fmaxf(v2,v3));
    float e0 = expf(v0-mx), e1 = expf(v1-mx), e2 = expf(v2-mx), e3 = expf(v3-mx);
    float inv = 1.0f / (e0+e1+e2+e3);
    wgt[b*16 + mrow*4 + 0] = e0*inv;
    wgt[b*16 + mrow*4 + 1] = e1*inv;
    wgt[b*16 + mrow*4 + 2] = e2*inv;
    wgt[b*16 + mrow*4 + 3] = e3*inv;
  }
}

// ---------------- combine: out = sum_e wgt[b][m][e] * h3[e] ----------------
// block = bmt row; thread t: o = t>>4, p-quad = (t&15)*4
__global__ __launch_bounds__(256) void combine_kernel(
    const f16* __restrict__ h3, const float* __restrict__ wgt,
    float* __restrict__ out)
{
  const int bmt = blockIdx.x;
  const int tile = bmt & 63, m = (bmt >> 6) & 3, b = bmt >> 8;
  const int t = threadIdx.x;
  const int o = t >> 4, pq = t & 15;

  const f32x4 w = *(const f32x4*)(wgt + (b*4 + m)*4);
  f32x4 s = {0.f, 0.f, 0.f, 0.f};
  #pragma unroll
  for (int e = 0; e < 4; ++e) {
    f16x4 h = *(const f16x4*)(h3 + (((size_t)(e*NBMT + bmt))*16 + o)*64 + pq*4);
    #pragma unroll
    for (int j = 0; j < 4; ++j) s[j] += w[e] * (float)h[j];
  }
  *(f32x4*)(out + (((size_t)b*16 + o)*4 + m)*4096 + tile*64 + pq*4) = s;
}

// ---------------- launcher ----------------
extern "C" void kernel_launch(void* const* d_in, const int* in_sizes, int n_in,
                              void* d_out, int out_size, void* d_ws, size_t ws_size,
                              hipStream_t stream) {
  const float* x   = (const float*)d_in[0];
  const float* W1  = (const float*)d_in[1];
  const float* b1  = (const float*)d_in[2];
  const float* W2  = (const float*)d_in[3];
  const float* b2  = (const float*)d_in[4];
  const float* W3  = (const float*)d_in[5];
  const float* b3  = (const float*)d_in[6];
  const float* Wg1 = (const float*)d_in[7];
  const float* bg1 = (const float*)d_in[8];
  const float* Wg2 = (const float*)d_in[9];
  const float* bg2 = (const float*)d_in[10];
  float* out = (float*)d_out;

  char* ws = (char*)d_ws;
  float* wgt    = (float*)ws;                      //      1024 B  [b][m][e]
  f16* W1s      = (f16*)(ws + 4096);               //    524288 B
  f16* W2s      = (f16*)(ws + 4096 + 524288);      //     49152 B
  f16* W3s      = (f16*)(ws + 4096 + 524288 + 49152); //   8192 B
  float* partial= (float*)(ws + (1u<<20));         //   8 MiB  [bmt][c]
  f16* h3       = (f16*)(ws + (16u<<20));          //  32 MiB  [e][bmt][o][p]

  prep_kernel<<<(262144 + 24576 + 4096 + 255)/256, 256, 0, stream>>>(W1, W2, W3, W1s, W2s, W3s);
  moe_kernel<<<NBMT, 512, 0, stream>>>(x, W1s, W2s, W3s, b1, b2, b3, partial, h3);
  gate_kernel<<<BDIM, 256, 0, stream>>>(partial, Wg1, bg1, Wg2, bg2, wgt);
  combine_kernel<<<NBMT, 256, 0, stream>>>(h3, wgt, out);
}

// Round 5
// 419.394 us; speedup vs baseline: 1.4911x; 1.4911x over previous
//
#include <hip/hip_runtime.h>

typedef _Float16 f16;
typedef f16 f16x8 __attribute__((ext_vector_type(8)));
typedef f16 f16x4 __attribute__((ext_vector_type(4)));
typedef f16 f16x2 __attribute__((ext_vector_type(2)));
typedef float f32x4 __attribute__((ext_vector_type(4)));

// sizes
#define BDIM 16
#define CDIM 512
#define MDIM 4
#define NDIM 4096
#define NB   64          // n-columns per tile
#define NTILES (NDIM/NB) // 64
#define NBMT  (BDIM*MDIM*NTILES)  // 4096 (b,m,tile) rows

// LDS swizzle: spreads rows p across 8 16B slots; bijective per row
#define SX(p) ((((p)&7) ^ (((p)>>3)&7)))

// ---------------- prep: fp32 weights -> f16 fragment layout ----------------
// W1s: [e][kb(64)][o(128)][ki(8)]  (k = kb*8+ki, K=512)
// W2s: [e][kb(16)][o(48)][ki(8)]   (K=128)
// W3s: [e][kb(8)][o(16)][ki(8)]    (K=64, zero-padded from 48)
__global__ __launch_bounds__(256) void prep_kernel(
    const float* __restrict__ W1, const float* __restrict__ W2, const float* __restrict__ W3,
    f16* __restrict__ W1s, f16* __restrict__ W2s, f16* __restrict__ W3s)
{
  int i = blockIdx.x * 256 + threadIdx.x;
  if (i < 262144) {
    int ki = i & 7; int rest = i >> 3;
    int o = rest & 127; rest >>= 7;
    int kb = rest & 63; int e = rest >> 6;
    W1s[i] = (f16)W1[(e*128 + o)*512 + kb*8 + ki];
  } else if (i < 262144 + 24576) {
    int j = i - 262144;
    int ki = j & 7; int rest = j >> 3;
    int o = rest % 48; rest /= 48;
    int kb = rest & 15; int e = rest >> 4;
    W2s[j] = (f16)W2[(e*48 + o)*128 + kb*8 + ki];
  } else if (i < 262144 + 24576 + 4096) {
    int j = i - 262144 - 24576;
    int ki = j & 7; int rest = j >> 3;
    int o = rest & 15; rest >>= 4;
    int kb = rest & 7; int e = rest >> 3;
    int k = kb*8 + ki;
    W3s[j] = (k < 48) ? (f16)W3[(e*16 + o)*48 + k] : (f16)0.f;
  }
}

// ---------------- fused MoE expert pass (+ pool partials) ----------------
// block = (b, m, 64 n-columns); 1024 threads = 16 waves; 1 block/CU (96 KiB LDS).
// Wave w: expert-half eh = w>>3 (experts 2eh, 2eh+1), o-strip o0 = (w&7)*16.
// acc[2][4] f32x4 = 32 VGPRs/lane  (vs 64 before -> regalloc fits <=128).
// Phase A: X in 2 K-halves (256 ch each) staged to LDS; half-1 prefetched into
//          regs during half-0 MFMA stream (T14). 64 MFMA per wave per half.
// Phase B: all 4 experts at once: H1 (overlays dead X region) -> L2 (48 frags,
//          3/wave) -> L3 (16 frags, 1/wave) -> h3 f16.
// LDS 96 KiB: X [2][64p][512B] (-> H1 [4e][64p][256B]) + H2 [4e][64p][128B].
__global__ __launch_bounds__(1024, 4) void moe_kernel(
    const float* __restrict__ x,
    const f16* __restrict__ W1s, const f16* __restrict__ W2s, const f16* __restrict__ W3s,
    const float* __restrict__ b1, const float* __restrict__ b2, const float* __restrict__ b3,
    float* __restrict__ partial, f16* __restrict__ h3)
{
  extern __shared__ char smem[];          // 98304 B
  char* H1t = smem;                       // Phase B alias of X region (64 KiB)
  char* H2t = smem + 65536;               // 32 KiB

  const int tid  = threadIdx.x;
  const int bid  = blockIdx.x;
  const int tile = bid & 63;
  const int m    = (bid >> 6) & 3;
  const int b    = bid >> 8;

  const int wave = tid >> 6, lane = tid & 63;
  const int g = lane >> 4, r = lane & 15;
  const int eh = wave >> 3;               // expert half: experts 2eh, 2eh+1
  const int o0 = (wave & 7) * 16;

  // zero H2 region once (provides K-pad h=48..63)
  {
    uint4 z = make_uint4(0u,0u,0u,0u);
    ((uint4*)H2t)[tid] = z;
    ((uint4*)H2t)[tid + 1024] = z;
  }

  // staging coords: thread covers channel pairs (2cp, 2cp+1) for cp in {cp0, cp0+64}
  // within a half; positions quad q*4..q*4+3.
  const int cp0 = tid >> 4;               // 0..63
  const int q   = tid & 15;               // 0..15
  const size_t xrow = ((size_t)(b*2048 + m))*4096 + (size_t)tile*64 + (size_t)(q*4);

  // ---- stage half 0 (channels 0..255) + pool partials
  #pragma unroll
  for (int it = 0; it < 2; ++it) {
    const int cp = cp0 + it*64;
    const int c  = 2*cp;                  // global channel (half 0)
    f32x4 v0 = *(const f32x4*)(x + xrow + (size_t)c*16384);
    f32x4 v1 = *(const f32x4*)(x + xrow + (size_t)(c+1)*16384);
    #pragma unroll
    for (int i = 0; i < 4; ++i) {
      int p = q*4 + i;
      f16x2 hv; hv[0] = (f16)v0[i]; hv[1] = (f16)v1[i];
      *(f16x2*)(smem + p*512 + ((4*cp) ^ (SX(p)<<4))) = hv;
    }
    float s0 = v0[0]+v0[1]+v0[2]+v0[3];
    float s1 = v1[0]+v1[1]+v1[2]+v1[3];
    #pragma unroll
    for (int off = 8; off; off >>= 1) {
      s0 += __shfl_down(s0, off, 16);
      s1 += __shfl_down(s1, off, 16);
    }
    if (q == 0) { float2 sv = {s0, s1}; *(float2*)(partial + (size_t)bid*512 + c) = sv; }
  }
  __syncthreads();

  f32x4 acc[2][4];
  #pragma unroll
  for (int i = 0; i < 2; ++i)
    #pragma unroll
    for (int pt = 0; pt < 4; ++pt) acc[i][pt] = (f32x4){0.f,0.f,0.f,0.f};

  // compute one K-half (8 ks steps * 2 experts * 4 pt = 64 MFMA)
  auto compute_half = [&](const char* Xb, int h) {
    #pragma unroll
    for (int ks = 0; ks < 8; ++ks) {
      const int kbh = ks*4 + g;           // kb within half, 0..31
      const int kbg = h*32 + kbh;         // global kb, 0..63
      f16x8 bf[4];
      #pragma unroll
      for (int pt = 0; pt < 4; ++pt) {
        int p = pt*16 + r;
        bf[pt] = *(const f16x8*)(Xb + p*512 + ((kbh*16) ^ (SX(p)<<4)));
      }
      #pragma unroll
      for (int i = 0; i < 2; ++i) {
        const int e = eh*2 + i;
        f16x8 a = *(const f16x8*)(W1s + ((size_t)((e*64 + kbg)*128) + o0 + r)*8);
        acc[i][0] = __builtin_amdgcn_mfma_f32_16x16x32_f16(a, bf[0], acc[i][0], 0, 0, 0);
        acc[i][1] = __builtin_amdgcn_mfma_f32_16x16x32_f16(a, bf[1], acc[i][1], 0, 0, 0);
        acc[i][2] = __builtin_amdgcn_mfma_f32_16x16x32_f16(a, bf[2], acc[i][2], 0, 0, 0);
        acc[i][3] = __builtin_amdgcn_mfma_f32_16x16x32_f16(a, bf[3], acc[i][3], 0, 0, 0);
      }
    }
  };

  // prefetch half 1 (channels 256..511) into regs, then compute half 0
  f32x4 nva0, nva1, nvb0, nvb1;
  {
    const int ca = 256 + 2*cp0;
    const int cb = 256 + 2*(cp0 + 64);
    nva0 = *(const f32x4*)(x + xrow + (size_t)ca*16384);
    nva1 = *(const f32x4*)(x + xrow + (size_t)(ca+1)*16384);
    nvb0 = *(const f32x4*)(x + xrow + (size_t)cb*16384);
    nvb1 = *(const f32x4*)(x + xrow + (size_t)(cb+1)*16384);
  }
  compute_half(smem, 0);

  // write half 1 + its pool partials
  {
    char* X1 = smem + 32768;
    #pragma unroll
    for (int i = 0; i < 4; ++i) {
      int p = q*4 + i;
      f16x2 ha; ha[0] = (f16)nva0[i]; ha[1] = (f16)nva1[i];
      *(f16x2*)(X1 + p*512 + ((4*cp0) ^ (SX(p)<<4))) = ha;
      f16x2 hb; hb[0] = (f16)nvb0[i]; hb[1] = (f16)nvb1[i];
      *(f16x2*)(X1 + p*512 + ((4*(cp0+64)) ^ (SX(p)<<4))) = hb;
    }
    float sa0 = nva0[0]+nva0[1]+nva0[2]+nva0[3];
    float sa1 = nva1[0]+nva1[1]+nva1[2]+nva1[3];
    float sb0 = nvb0[0]+nvb0[1]+nvb0[2]+nvb0[3];
    float sb1 = nvb1[0]+nvb1[1]+nvb1[2]+nvb1[3];
    #pragma unroll
    for (int off = 8; off; off >>= 1) {
      sa0 += __shfl_down(sa0, off, 16);
      sa1 += __shfl_down(sa1, off, 16);
      sb0 += __shfl_down(sb0, off, 16);
      sb1 += __shfl_down(sb1, off, 16);
    }
    if (q == 0) {
      float2 sva = {sa0, sa1};
      float2 svb = {sb0, sb1};
      *(float2*)(partial + (size_t)bid*512 + 256 + 2*cp0)       = sva;
      *(float2*)(partial + (size_t)bid*512 + 256 + 2*(cp0+64))  = svb;
    }
  }
  __syncthreads();
  compute_half(smem + 32768, 1);
  __syncthreads();                        // X region dead -> reuse as H1

  // ---- Phase B, step 1: H1 = relu(acc + b1) -> LDS [e][p][o]
  #pragma unroll
  for (int i = 0; i < 2; ++i) {
    const int e = eh*2 + i;
    const f32x4 bias = *(const f32x4*)(b1 + e*128 + o0 + g*4);
    const int colb = (o0 + g*4)*2;
    #pragma unroll
    for (int pt = 0; pt < 4; ++pt) {
      int p = pt*16 + r;
      f16x4 hv;
      #pragma unroll
      for (int j = 0; j < 4; ++j) hv[j] = (f16)fmaxf(acc[i][pt][j] + bias[j], 0.f);
      *(f16x4*)(H1t + e*16384 + p*256 + (colb ^ (SX(p)<<4))) = hv;
    }
  }
  __syncthreads();

  // ---- Phase B, step 2: L2 (48 fragments = 4e x 3ot x 4pt, 3 per wave)
  #pragma unroll
  for (int s = 0; s < 3; ++s) {
    const int f  = wave*3 + s;
    const int e  = f / 12;
    const int ot = (f % 12) >> 2;
    const int pt = f & 3;
    const int p  = pt*16 + r;
    f32x4 acc2 = {0.f,0.f,0.f,0.f};
    #pragma unroll
    for (int ks = 0; ks < 4; ++ks) {
      const int kb = ks*4 + g;
      f16x8 a  = *(const f16x8*)(W2s + (size_t)((e*16 + kb)*48 + ot*16 + r)*8);
      f16x8 bf = *(const f16x8*)(H1t + e*16384 + p*256 + ((kb*16) ^ (SX(p)<<4)));
      acc2 = __builtin_amdgcn_mfma_f32_16x16x32_f16(a, bf, acc2, 0, 0, 0);
    }
    const f32x4 bias = *(const f32x4*)(b2 + e*48 + ot*16 + g*4);
    const int colb = (ot*16 + g*4)*2;
    f16x4 hv;
    #pragma unroll
    for (int j = 0; j < 4; ++j) hv[j] = (f16)fmaxf(acc2[j] + bias[j], 0.f);
    *(f16x4*)(H2t + e*8192 + p*128 + (colb ^ (SX(p)<<4))) = hv;
  }
  __syncthreads();

  // ---- Phase B, step 3: L3 (16 fragments = 4e x 4pt, 1 per wave) -> h3
  {
    const int e  = wave >> 2;
    const int pt = wave & 3;
    const int p  = pt*16 + r;
    f32x4 acc3 = {0.f,0.f,0.f,0.f};
    #pragma unroll
    for (int ks = 0; ks < 2; ++ks) {
      const int kb = ks*4 + g;
      f16x8 a  = *(const f16x8*)(W3s + (size_t)((e*8 + kb)*16 + r)*8);
      f16x8 bf = *(const f16x8*)(H2t + e*8192 + p*128 + ((kb*16) ^ (SX(p)<<4)));
      acc3 = __builtin_amdgcn_mfma_f32_16x16x32_f16(a, bf, acc3, 0, 0, 0);
    }
    const f32x4 bias = *(const f32x4*)(b3 + e*16 + g*4);
    #pragma unroll
    for (int j = 0; j < 4; ++j) {
      int o = g*4 + j;
      h3[(((size_t)(e*NBMT + bid))*16 + o)*64 + pt*16 + r] = (f16)(acc3[j] + bias[j]);
    }
  }
}

// ---------------- gate: reduce partials -> pooled, MLP + softmax ----------
__global__ __launch_bounds__(256) void gate_kernel(
    const float* __restrict__ partial, const float* __restrict__ Wg1,
    const float* __restrict__ bg1, const float* __restrict__ Wg2,
    const float* __restrict__ bg2, float* __restrict__ wgt)
{
  __shared__ float pl[512*4];   // [c][m]
  __shared__ float g1[128*4];   // [o][m]
  __shared__ float g2[16];      // [e][m]
  const int b = blockIdx.x, tid = threadIdx.x;

  // reduce 64 tile-partials per (m, c): thread owns c-pair c0, c0+1
  const int c0 = tid * 2;
  #pragma unroll
  for (int mm = 0; mm < 4; ++mm) {
    const float* base = partial + ((size_t)((b*4 + mm)*64))*512 + c0;
    float a0 = 0.f, a1 = 0.f;
    for (int tl = 0; tl < 64; ++tl) {
      float2 v = *(const float2*)(base + tl*512);
      a0 += v.x; a1 += v.y;
    }
    pl[(c0+0)*4 + mm] = a0 * (1.0f/4096.0f);
    pl[(c0+1)*4 + mm] = a1 * (1.0f/4096.0f);
  }
  __syncthreads();

  #pragma unroll
  for (int u = 0; u < 2; ++u) {
    int idx = u*256 + tid;
    int o = idx >> 2, mm = idx & 3;
    float acc = bg1[o];
    for (int c = 0; c < 512; ++c) acc += Wg1[o*512 + c] * pl[c*4 + mm];
    g1[o*4 + mm] = fmaxf(acc, 0.f);
  }
  __syncthreads();
  if (tid < 16) {
    int e = tid >> 2, mm = tid & 3;
    float acc = bg2[e];
    for (int o = 0; o < 128; ++o) acc += Wg2[e*128 + o] * g1[o*4 + mm];
    g2[e*4 + mm] = acc;
  }
  __syncthreads();
  if (tid < 4) {
    // weights[b][m][e] = softmax_e over G[m][e], G[m][e] = g2[expert=m][modal=e]
    int mrow = tid;
    float v0 = g2[mrow*4+0], v1 = g2[mrow*4+1], v2 = g2[mrow*4+2], v3 = g2[mrow*4+3];
    float mx = fmaxf(fmaxf(v0,v1), fmaxf(v2,v3));
    float e0 = expf(v0-mx), e1 = expf(v1-mx), e2 = expf(v2-mx), e3 = expf(v3-mx);
    float inv = 1.0f / (e0+e1+e2+e3);
    wgt[b*16 + mrow*4 + 0] = e0*inv;
    wgt[b*16 + mrow*4 + 1] = e1*inv;
    wgt[b*16 + mrow*4 + 2] = e2*inv;
    wgt[b*16 + mrow*4 + 3] = e3*inv;
  }
}

// ---------------- combine: out = sum_e wgt[b][m][e] * h3[e] ----------------
// block = bmt row; thread t: o = t>>4, p-quad = (t&15)*4
__global__ __launch_bounds__(256) void combine_kernel(
    const f16* __restrict__ h3, const float* __restrict__ wgt,
    float* __restrict__ out)
{
  const int bmt = blockIdx.x;
  const int tile = bmt & 63, m = (bmt >> 6) & 3, b = bmt >> 8;
  const int t = threadIdx.x;
  const int o = t >> 4, pq = t & 15;

  const f32x4 w = *(const f32x4*)(wgt + (b*4 + m)*4);
  f32x4 s = {0.f, 0.f, 0.f, 0.f};
  #pragma unroll
  for (int e = 0; e < 4; ++e) {
    f16x4 h = *(const f16x4*)(h3 + (((size_t)(e*NBMT + bmt))*16 + o)*64 + pq*4);
    #pragma unroll
    for (int j = 0; j < 4; ++j) s[j] += w[e] * (float)h[j];
  }
  *(f32x4*)(out + (((size_t)b*16 + o)*4 + m)*4096 + tile*64 + pq*4) = s;
}

// ---------------- launcher ----------------
extern "C" void kernel_launch(void* const* d_in, const int* in_sizes, int n_in,
                              void* d_out, int out_size, void* d_ws, size_t ws_size,
                              hipStream_t stream) {
  const float* x   = (const float*)d_in[0];
  const float* W1  = (const float*)d_in[1];
  const float* b1  = (const float*)d_in[2];
  const float* W2  = (const float*)d_in[3];
  const float* b2  = (const float*)d_in[4];
  const float* W3  = (const float*)d_in[5];
  const float* b3  = (const float*)d_in[6];
  const float* Wg1 = (const float*)d_in[7];
  const float* bg1 = (const float*)d_in[8];
  const float* Wg2 = (const float*)d_in[9];
  const float* bg2 = (const float*)d_in[10];
  float* out = (float*)d_out;

  char* ws = (char*)d_ws;
  float* wgt    = (float*)ws;                      //      1024 B  [b][m][e]
  f16* W1s      = (f16*)(ws + 4096);               //    524288 B
  f16* W2s      = (f16*)(ws + 4096 + 524288);      //     49152 B
  f16* W3s      = (f16*)(ws + 4096 + 524288 + 49152); //   8192 B
  float* partial= (float*)(ws + (1u<<20));         //   8 MiB  [bmt][c]
  f16* h3       = (f16*)(ws + (16u<<20));          //  32 MiB  [e][bmt][o][p]

  hipFuncSetAttribute(reinterpret_cast<const void*>(moe_kernel),
                      hipFuncAttributeMaxDynamicSharedMemorySize, 98304);

  prep_kernel<<<(262144 + 24576 + 4096 + 255)/256, 256, 0, stream>>>(W1, W2, W3, W1s, W2s, W3s);
  moe_kernel<<<NBMT, 1024, 98304, stream>>>(x, W1s, W2s, W3s, b1, b2, b3, partial, h3);
  gate_kernel<<<BDIM, 256, 0, stream>>>(partial, Wg1, bg1, Wg2, bg2, wgt);
  combine_kernel<<<NBMT, 256, 0, stream>>>(h3, wgt, out);
}